// Round 6
// baseline (180.926 us; speedup 1.0000x reference)
//
#include <hip/hip_runtime.h>

#define IMG 512
#define NB 8            // 16-row bands per block (128 rows/block)

// Gaussian window, sigma=1.5, ws=11, normalized (matches reference _make_window)
#define W0f 1.0283800e-03f
#define W1f 7.5987582e-03f
#define W2f 3.6000773e-02f
#define W3f 1.0936070e-01f
#define W4f 2.1300553e-01f
#define W5f 2.6601172e-01f

typedef _Float16 h1;
typedef h1 h2 __attribute__((ext_vector_type(2)));
typedef float f2 __attribute__((ext_vector_type(2)));

__device__ __forceinline__ f2 pkfma(f2 a, f2 b, f2 c) {
    return __builtin_elementwise_fma(a, b, c);
}

// Raw workgroup barrier: drain LDS only, leave global loads in flight.
#define LGKM_BARRIER() asm volatile("s_waitcnt lgkmcnt(0)\n\ts_barrier" ::: "memory")

__global__ __launch_bounds__(256, 4)
void ssim_main(const float* __restrict__ img1, const float* __restrict__ img2,
               float* __restrict__ part)
{
    // Ring: 64 slots x 64 px x 8 B = 32 KB exactly. Px = (x,y,s,p) as 4 f16
    // (s = x^2+y^2, p = x*y after h-blur). slot(gr) = gr & 63.
    // ALL arithmetic f32 (f16 accumulation is biased ~2e-5 in sigma12, x45 gain
    // -> 1e-3 final error, measured R5). Only STORAGE is f16 (RN, unbiased).
    __shared__ float4 ringRaw[64 * 32];
    float2* const rp2 = (float2*)ringRaw;

    const float Wt[11] = {W0f,W1f,W2f,W3f,W4f,W5f,W4f,W3f,W2f,W1f,W0f};
    constexpr float C1 = 1.0e-4f, C2 = 9.0e-4f;

    const int bx     = blockIdx.x;
    const int n      = bx >> 5;            // image 0..63
    const int stripe = (bx >> 2) & 7;      // 64-col stripe
    const int q      = bx & 3;             // row quarter
    const int gx0    = stripe << 6;
    const int base   = q << 7;
    const int tid    = threadIdx.x;
    const bool edge  = (stripe == 0) | (stripe == 7);

    const float* __restrict__ b1p = img1 + (size_t)n * IMG * IMG;
    const float* __restrict__ b2p = img2 + (size_t)n * IMG * IMG;

    float acc = 0.f;

    // ---- load 20-col window (5 aligned float4 per image), predicated
    auto loadRow = [&](int gr, int gcb, float4* PX, float4* PY) {
        const float* r1 = b1p + (ptrdiff_t)gr * IMG + (gcb - 8);
        const float* r2 = b2p + (ptrdiff_t)gr * IMG + (gcb - 8);
        const bool rok = (unsigned)gr < (unsigned)IMG;
        if (rok & (!edge)) {
            #pragma unroll
            for (int t = 0; t < 5; ++t) {
                PX[t] = ((const float4*)r1)[t];
                PY[t] = ((const float4*)r2)[t];
            }
        } else {
            #pragma unroll
            for (int t = 0; t < 5; ++t) {
                int gc = gcb - 8 + (t << 2);
                bool ok = rok && (gc >= 0) && (gc <= IMG - 4);
                PX[t] = ok ? ((const float4*)r1)[t] : make_float4(0.f,0.f,0.f,0.f);
                PY[t] = ok ? ((const float4*)r2)[t] : make_float4(0.f,0.f,0.f,0.f);
            }
        }
    };

    // ---- h-blur (f32) of preloaded row -> f16 ring row, 4 cols (c0..c0+3),
    // stored as two px-pair b128 writes (16 lanes x 32B stride -> 2-way, free)
    auto horizStore = [&](int gr, int cg, const float4* PX, const float4* PY) {
        float X[20], Y[20];
        #pragma unroll
        for (int t = 0; t < 5; ++t) {
            X[4*t]=PX[t].x; X[4*t+1]=PX[t].y; X[4*t+2]=PX[t].z; X[4*t+3]=PX[t].w;
            Y[4*t]=PY[t].x; Y[4*t+1]=PY[t].y; Y[4*t+2]=PY[t].z; Y[4*t+3]=PY[t].w;
        }
        f2 pxy[14], psp[14];
        #pragma unroll
        for (int j = 0; j < 14; ++j) {
            float x = X[3+j], y = Y[3+j];
            pxy[j] = f2{x, y};
            psp[j] = f2{fmaf(x, x, y*y), x*y};
        }
        f2 axy[4], asp[4];
        #pragma unroll
        for (int o = 0; o < 4; ++o) {
            f2 m = {0.f,0.f}, t2 = {0.f,0.f};
            #pragma unroll
            for (int k = 0; k < 11; ++k) {
                f2 w2 = {Wt[k], Wt[k]};
                m  = pkfma(w2, pxy[o+k], m);
                t2 = pkfma(w2, psp[o+k], t2);
            }
            axy[o] = m; asp[o] = t2;
        }
        // pack: px = (h16 x, h16 y, h16 s, h16 p) -- RN casts (bias-free)
        const int slot = (gr + 64) & 63;
        float4* dst = ringRaw + (slot << 5) + (cg << 1);
        #pragma unroll
        for (int pp = 0; pp < 2; ++pp) {
            float4 st;
            h2 a0 = h2{(h1)axy[2*pp].x,   (h1)axy[2*pp].y};
            h2 b0 = h2{(h1)asp[2*pp].x,   (h1)asp[2*pp].y};
            h2 a1 = h2{(h1)axy[2*pp+1].x, (h1)axy[2*pp+1].y};
            h2 b1 = h2{(h1)asp[2*pp+1].x, (h1)asp[2*pp+1].y};
            st.x = __builtin_bit_cast(float, a0);
            st.y = __builtin_bit_cast(float, b0);
            st.z = __builtin_bit_cast(float, a1);
            st.w = __builtin_bit_cast(float, b1);
            dst[pp] = st;
        }
    };

    // ---- vert blur + SSIM: 4 rows/thread, f16 loads, f32 accumulation (mix)
    auto vert = [&](int b) {
        const int wv  = __builtin_amdgcn_readfirstlane(tid >> 6);
        const int col = tid & 63;
        const int gr0 = base + (b << 4) + (wv << 2) - 5 + 64;   // >= 0
        h2 vxy[14], vsp[14];
        #pragma unroll
        for (int i = 0; i < 14; ++i) {
            const int slot = (gr0 + i) & 63;                    // scalar
            float2 qv = rp2[(slot << 6) + col];                 // ds_read_b64
            vxy[i] = __builtin_bit_cast(h2, qv.x);
            vsp[i] = __builtin_bit_cast(h2, qv.y);
        }
        #pragma unroll
        for (int qd = 0; qd < 4; ++qd) {
            float m1=0.f, m2=0.f, ts=0.f, tp=0.f;
            #pragma unroll
            for (int k = 0; k < 11; ++k) {
                const float w = Wt[k];
                m1 = fmaf((float)vxy[qd+k].x, w, m1);   // v_fma_mix_f32
                m2 = fmaf((float)vxy[qd+k].y, w, m2);
                ts = fmaf((float)vsp[qd+k].x, w, ts);
                tp = fmaf((float)vsp[qd+k].y, w, tp);
            }
            float mu12  = m1 * m2;
            float musum = fmaf(m1, m1, m2*m2);
            float g12 = tp - mu12;                      // sigma12
            float gs  = ts - musum;                     // sigma1^2+sigma2^2
            float num = fmaf(2.f, mu12, C1) * fmaf(2.f, g12, C2);
            float den = (musum + C1) * (gs + C2);
            acc = fmaf(num, __builtin_amdgcn_rcpf(den), acc);
        }
    };

    const int ri  = tid >> 4;              // staging row 0..15
    const int cg  = tid & 15;              // staging col-group (4 cols)
    const int gcb = gx0 + (cg << 2);

    // ---- prologue: stage rows base-5 .. base+20 (26 rows x 16 col-groups)
    {
        float4 PX[5], PY[5];
        int gr = base - 5 + ri;
        loadRow(gr, gcb, PX, PY);
        horizStore(gr, cg, PX, PY);
        int task = tid + 256;              // rows 16..25
        if (task < 26 * 16) {
            int gr2 = base - 5 + (task >> 4);
            int cg2 = task & 15;
            loadRow(gr2, gx0 + (cg2 << 2), PX, PY);
            horizStore(gr2, cg2, PX, PY);
        }
    }

    // ---- initial prefetch: rows base+21..base+36 (consumed by store at b=0)
    float4 PX[5], PY[5];
    loadRow(base + 21 + ri, gcb, PX, PY);

    // ---- main loop: 1 barrier/band.
    // Stores (rows r0+21..r0+36) are mod-64 disjoint from vert(b)'s window
    // (rows r0-5..r0+20): span 42 < 64 -> no WAR, stores overlap vert.
    // Prefetch for band b+1's store is issued a full band ahead.
    for (int b = 0; b < NB; ++b) {
        const int r0 = base + (b << 4);
        LGKM_BARRIER();                    // ring rows <= r0+20 visible
        if (b < NB-1) horizStore(r0 + 21 + ri, cg, PX, PY);
        if (b < NB-2) loadRow(r0 + 37 + ri, gcb, PX, PY);   // in flight thru vert
        vert(b);
    }

    // ---- block reduction (reuse ring LDS after final barrier)
    #pragma unroll
    for (int off = 32; off > 0; off >>= 1)
        acc += __shfl_down(acc, off, 64);
    LGKM_BARRIER();                        // last vert reads complete
    if ((tid & 63) == 0) ((float*)ringRaw)[tid >> 6] = acc;
    LGKM_BARRIER();
    if (tid == 0) {
        const float* r = (const float*)ringRaw;
        part[bx] = r[0] + r[1] + r[2] + r[3];
    }
}

__global__ void ssim_finalize(const float* __restrict__ part, float* __restrict__ out)
{
    double s = 0.0;
    const int t = threadIdx.x;
    for (int i = t; i < 2048; i += 64) s += (double)part[i];
    #pragma unroll
    for (int off = 32; off > 0; off >>= 1)
        s += __shfl_down(s, off, 64);
    if (t == 0) out[0] = (float)(s * (1.0 / 16777216.0));
}

extern "C" void kernel_launch(void* const* d_in, const int* in_sizes, int n_in,
                              void* d_out, int out_size, void* d_ws, size_t ws_size,
                              hipStream_t stream)
{
    const float* img1 = (const float*)d_in[0];
    const float* img2 = (const float*)d_in[1];
    float* out  = (float*)d_out;
    float* part = (float*)d_ws;      // 2048 floats of scratch

    ssim_main<<<2048, 256, 0, stream>>>(img1, img2, part);
    ssim_finalize<<<1, 64, 0, stream>>>(part, out);
}